// Round 1
// baseline (22002.554 us; speedup 1.0000x reference)
//
#include <hip/hip_runtime.h>
#include <cmath>

#define HID 512
#define NEXP 128
#define BB 4
#define SS 2048
#define NROW (BB*SS)      // 8192
#define SCAN_BLOCKS 128   // 32 blocks per batch chain

__device__ __forceinline__ float gelu_f(float x){
  return 0.5f*x*(1.0f + erff(x*0.70710678118654752440f));
}

__device__ __forceinline__ float aload(const float* p){
  return __hip_atomic_load(p, __ATOMIC_RELAXED, __HIP_MEMORY_SCOPE_AGENT);
}
__device__ __forceinline__ void astore(float* p, float v){
  __hip_atomic_store(p, v, __ATOMIC_RELAXED, __HIP_MEMORY_SCOPE_AGENT);
}

// ---------------- pack: W1cat=[w_ff1_bot | w_rw], W3=w_ta+w_tb, b3, biwc ----
__global__ __launch_bounds__(256) void pack_k(
    const float* __restrict__ w_ff1, const float* __restrict__ w_rw,
    const float* __restrict__ w_ta, const float* __restrict__ w_tb,
    const float* __restrict__ b_ta, const float* __restrict__ b_tb,
    const float* __restrict__ b_iw, const float* __restrict__ input_b,
    float* __restrict__ W1cat, float* __restrict__ W3,
    float* __restrict__ b3, float* __restrict__ biwc)
{
  int idx = blockIdx.x*256 + threadIdx.x;       // 0..524287
  int k = idx >> 10, c = idx & 1023;
  W1cat[idx] = (c < HID) ? w_ff1[(size_t)(HID+k)*HID + c]
                         : w_rw[(size_t)k*HID + (c-HID)];
  if (idx < HID*HID) W3[idx] = w_ta[idx] + w_tb[idx];
  if (idx < HID) { b3[idx] = b_ta[idx] + b_tb[idx]; biwc[idx] = b_iw[idx] + input_b[idx]; }
}

// ---------------- generic fp32 GEMM: C = A(MxK) @ W(KxN) + bias (opt gelu) --
template<bool GELU>
__global__ __launch_bounds__(256) void gemm_k(
    const float* __restrict__ A, const float* __restrict__ W,
    const float* __restrict__ bias, float* __restrict__ C,
    int M, int N, int K)
{
  __shared__ float As[16][68];
  __shared__ float Ws[16][68];
  const int tid = threadIdx.x;
  const int mb = blockIdx.y*64, nb = blockIdx.x*64;
  const int tx = tid & 15, ty = tid >> 4;
  const int am = tid >> 2, ak = (tid & 3)*4;
  const int wk = tid >> 4, wn = (tid & 15)*4;
  float acc[4][4] = {};
  const float* Aptr = A + (size_t)(mb+am)*K + ak;
  for (int kt = 0; kt < K; kt += 16){
    float4 av = *(const float4*)(Aptr + kt);
    float4 wv = *(const float4*)(W + (size_t)(kt+wk)*N + nb + wn);
    As[ak  ][am] = av.x; As[ak+1][am] = av.y; As[ak+2][am] = av.z; As[ak+3][am] = av.w;
    *(float4*)&Ws[wk][wn] = wv;
    __syncthreads();
#pragma unroll
    for (int kk = 0; kk < 16; kk++){
      float4 a4 = *(const float4*)&As[kk][ty*4];
      float4 w4 = *(const float4*)&Ws[kk][tx*4];
      float ar[4] = {a4.x, a4.y, a4.z, a4.w};
      float wr[4] = {w4.x, w4.y, w4.z, w4.w};
#pragma unroll
      for (int i = 0; i < 4; i++)
#pragma unroll
        for (int j = 0; j < 4; j++)
          acc[i][j] = fmaf(ar[i], wr[j], acc[i][j]);
    }
    __syncthreads();
  }
#pragma unroll
  for (int i = 0; i < 4; i++){
    int row = mb + ty*4 + i;
    float o[4];
#pragma unroll
    for (int j = 0; j < 4; j++){
      float v = acc[i][j] + bias[nb + tx*4 + j];
      o[j] = GELU ? gelu_f(v) : v;
    }
    float4 o4 = {o[0], o[1], o[2], o[3]};
    *(float4*)(C + (size_t)row*N + nb + tx*4) = o4;
  }
}

// ---------------- per-batch-group grid barrier -------------------------------
__device__ __forceinline__ void gridbar(int* mybar, int e, int sub){
  __syncthreads();
  if (threadIdx.x == 0){
    __hip_atomic_store(&mybar[sub], e, __ATOMIC_RELEASE, __HIP_MEMORY_SCOPE_AGENT);
  }
  if (threadIdx.x < 64){
    int l = threadIdx.x & 31;
    for (;;){
      int v = __hip_atomic_load(&mybar[l], __ATOMIC_RELAXED, __HIP_MEMORY_SCOPE_AGENT);
      if (__all(v >= e)) break;
      __builtin_amdgcn_s_sleep(1);
    }
  }
  __syncthreads();
}

// ---------------- sequential h-recurrence ------------------------------------
__global__ __launch_bounds__(256) void scan_k(
    const float* __restrict__ W1cat, const float* __restrict__ W2,
    const float* __restrict__ bff2, const float* __restrict__ W3,
    const float* __restrict__ b3, const float* __restrict__ rb,
    const float* __restrict__ PRE, const float* __restrict__ INPC,
    float* __restrict__ Hout,
    float* hbuf, float* ff1g, float* ff2g, float* recg, int* bar)
{
  const int tid = threadIdx.x;
  const int bid = blockIdx.x;
  const int b = bid >> 5, sub = bid & 31;
  __shared__ float stg[512];
  __shared__ float red[128];
  int* mybar = bar + b*32;
  int epoch = 0;

  const int cA = tid & 31, pA = tid >> 5;      // stage A: col-in-block, ksplit-8
  const int cgA = sub*32 + cA;                 // global col in [0,1024)
  const int jB = tid & 15, qB = tid >> 4;      // stages B/C: col, ksplit-16
  const int jgB = sub*16 + jB;                 // global col in [0,512)

  for (int t = 0; t < SS; t++){
    // ---- stage h into LDS ----
    stg[tid]     = aload(&hbuf[b*HID + tid]);
    stg[tid+256] = aload(&hbuf[b*HID + tid + 256]);
    __syncthreads();
    // ---- stage A: u = h @ [W_ff1_bot | W_rw] ----
    {
      const float* wp = W1cat + (size_t)(pA*64)*1024 + cgA;
      const float* hp = stg + pA*64;
      float a0=0.f, a1=0.f, a2=0.f, a3=0.f;
#pragma unroll
      for (int i = 0; i < 64; i += 4){
        a0 = fmaf(wp[(size_t)(i  )*1024], hp[i  ], a0);
        a1 = fmaf(wp[(size_t)(i+1)*1024], hp[i+1], a1);
        a2 = fmaf(wp[(size_t)(i+2)*1024], hp[i+2], a2);
        a3 = fmaf(wp[(size_t)(i+3)*1024], hp[i+3], a3);
      }
      float acc = (a0+a1)+(a2+a3);
      acc += __shfl_xor(acc, 32);
      if ((tid & 32) == 0) red[(tid>>6)*32 + cA] = acc;
    }
    __syncthreads();
    if (tid < 32){
      float s = red[tid] + red[32+tid] + red[64+tid] + red[96+tid];
      int cg = sub*32 + tid;
      if (cg < HID){
        astore(&ff1g[b*HID + cg], gelu_f(PRE[((size_t)b*SS + t)*HID + cg] + s));
      } else {
        int r = cg - HID;
        astore(&recg[b*HID + r], gelu_f(s + rb[r]));
      }
    }
    gridbar(mybar, ++epoch, sub);

    // ---- stage B: ff2 = gelu(ff1 @ W_ff2 + b) ----
    stg[tid]     = aload(&ff1g[b*HID + tid]);
    stg[tid+256] = aload(&ff1g[b*HID + tid + 256]);
    __syncthreads();
    {
      const float* wp = W2 + (size_t)(qB*32)*HID + jgB;
      const float* fp = stg + qB*32;
      float a0=0.f, a1=0.f, a2=0.f, a3=0.f;
#pragma unroll
      for (int i = 0; i < 32; i += 4){
        a0 = fmaf(wp[(size_t)(i  )*HID], fp[i  ], a0);
        a1 = fmaf(wp[(size_t)(i+1)*HID], fp[i+1], a1);
        a2 = fmaf(wp[(size_t)(i+2)*HID], fp[i+2], a2);
        a3 = fmaf(wp[(size_t)(i+3)*HID], fp[i+3], a3);
      }
      float acc = (a0+a1)+(a2+a3);
      acc += __shfl_xor(acc, 16);
      acc += __shfl_xor(acc, 32);
      if ((tid & 48) == 0) red[(tid>>6)*16 + jB] = acc;
    }
    __syncthreads();
    if (tid < 16){
      float s = red[tid] + red[16+tid] + red[32+tid] + red[48+tid];
      int jg = sub*16 + tid;
      astore(&ff2g[b*HID + jg], gelu_f(s + bff2[jg]));
    }
    gridbar(mybar, ++epoch, sub);

    // ---- stage C: t_interp + new_h ----
    stg[tid]     = aload(&ff2g[b*HID + tid]);
    stg[tid+256] = aload(&ff2g[b*HID + tid + 256]);
    __syncthreads();
    {
      const float* wp = W3 + (size_t)(qB*32)*HID + jgB;
      const float* fp = stg + qB*32;
      float a0=0.f, a1=0.f, a2=0.f, a3=0.f;
#pragma unroll
      for (int i = 0; i < 32; i += 4){
        a0 = fmaf(wp[(size_t)(i  )*HID], fp[i  ], a0);
        a1 = fmaf(wp[(size_t)(i+1)*HID], fp[i+1], a1);
        a2 = fmaf(wp[(size_t)(i+2)*HID], fp[i+2], a2);
        a3 = fmaf(wp[(size_t)(i+3)*HID], fp[i+3], a3);
      }
      float acc = (a0+a1)+(a2+a3);
      acc += __shfl_xor(acc, 16);
      acc += __shfl_xor(acc, 32);
      if ((tid & 48) == 0) red[(tid>>6)*16 + jB] = acc;
    }
    __syncthreads();
    if (tid < 16){
      float s = red[tid] + red[16+tid] + red[32+tid] + red[48+tid];
      int jg = sub*16 + tid;
      float ti = 1.0f / (1.0f + expf(-(s + b3[jg])));
      float h  = aload(&hbuf[b*HID + jg]);
      float rc = aload(&recg[b*HID + jg]);
      float ic = INPC[((size_t)b*SS + t)*HID + jg];
      float nh = h*(1.0f - ti) + ti*(ic + rc);
      astore(&hbuf[b*HID + jg], nh);
      Hout[((size_t)b*SS + t)*HID + jg] = nh;
    }
    gridbar(mybar, ++epoch, sub);
  }
}

// ---------------- softmax over 128 experts ----------------------------------
__global__ __launch_bounds__(256) void softmax_k(const float* __restrict__ LOGITS,
                                                 float* __restrict__ SM)
{
  int wv = threadIdx.x >> 6, lane = threadIdx.x & 63;
  int row = blockIdx.x*4 + wv;
  const float* xp = LOGITS + (size_t)row*NEXP;
  float x0 = xp[lane], x1 = xp[lane+64];
  float m = fmaxf(x0, x1);
#pragma unroll
  for (int d = 1; d < 64; d <<= 1) m = fmaxf(m, __shfl_xor(m, d));
  float e0 = expf(x0 - m), e1 = expf(x1 - m);
  float s = e0 + e1;
#pragma unroll
  for (int d = 1; d < 64; d <<= 1) s += __shfl_xor(s, d);
  float inv = 1.0f / s;
  float* op = SM + (size_t)row*NEXP;
  op[lane] = e0*inv; op[lane+64] = e1*inv;
}

// ---------------- smoothing (20-term window == exact recurrence) + top2 -----
__global__ __launch_bounds__(256) void smooth_topk_k(const float* __restrict__ SM,
                                                     float* __restrict__ out)
{
  int wv = threadIdx.x >> 6, lane = threadIdx.x & 63;
  int row = blockIdx.x*4 + wv;
  int b = row >> 11, t = row & 2047;
  const float* base = SM + (size_t)row*NEXP;
  float a0 = 0.f, a1 = 0.f;
  float coef = 0.9f;
  int nt = t < 20 ? t : 20;
  for (int j = 0; j < nt; j++){
    const float* pj = base - j*NEXP;
    a0 += coef * pj[lane];
    a1 += coef * pj[lane+64];
    coef *= 0.1f;
  }
  if (t < 20){
    const float* s0 = SM + (size_t)b*SS*NEXP;
    float c0 = coef * (1.0f/0.9f);    // 0.1^t
    a0 += c0 * s0[lane];
    a1 += c0 * s0[lane+64];
  }
  // per-lane sorted pair (ties -> lower index first)
  float v0, v1; int i0, i1;
  if (a0 >= a1){ v0=a0; i0=lane;    v1=a1; i1=lane+64; }
  else         { v0=a1; i0=lane+64; v1=a0; i1=lane;    }
#pragma unroll
  for (int d = 1; d < 64; d <<= 1){
    float ov0 = __shfl_xor(v0, d), ov1 = __shfl_xor(v1, d);
    int   oi0 = __shfl_xor(i0, d), oi1 = __shfl_xor(i1, d);
    bool firstMine = (v0 > ov0) || (v0 == ov0 && i0 < oi0);
    float nv0, nv1; int ni0, ni1;
    if (firstMine){
      nv0 = v0; ni0 = i0;
      bool s = (v1 > ov0) || (v1 == ov0 && i1 < oi0);
      nv1 = s ? v1 : ov0; ni1 = s ? i1 : oi0;
    } else {
      nv0 = ov0; ni0 = oi0;
      bool s = (ov1 > v0) || (ov1 == v0 && oi1 < i0);
      nv1 = s ? ov1 : v0; ni1 = s ? oi1 : i0;
    }
    v0 = nv0; v1 = nv1; i0 = ni0; i1 = ni1;
  }
  if (lane == 0){
    float ssum = v0 + v1;
    size_t o = (size_t)row*2;
    out[o]     = (float)i0;
    out[o+1]   = (float)i1;
    out[16384 + o]   = v0 / ssum;
    out[16384 + o+1] = v1 / ssum;
  }
}

// ---------------- host launch ------------------------------------------------
extern "C" void kernel_launch(void* const* d_in, const int* in_sizes, int n_in,
                              void* d_out, int out_size, void* d_ws, size_t ws_size,
                              hipStream_t stream)
{
  (void)in_sizes; (void)n_in; (void)out_size;
  const float* x       = (const float*)d_in[0];
  const float* w_in    = (const float*)d_in[1];
  const float* b_in    = (const float*)d_in[2];
  const float* w_ff1   = (const float*)d_in[3];
  const float* b_ff1   = (const float*)d_in[4];
  const float* w_ff2   = (const float*)d_in[5];
  const float* b_ff2   = (const float*)d_in[6];
  const float* w_ta    = (const float*)d_in[7];
  const float* b_ta    = (const float*)d_in[8];
  const float* w_tb    = (const float*)d_in[9];
  const float* b_tb    = (const float*)d_in[10];
  const float* w_iw    = (const float*)d_in[11];
  const float* b_iw    = (const float*)d_in[12];
  const float* input_b = (const float*)d_in[13];
  const float* w_rw    = (const float*)d_in[14];
  const float* r_b     = (const float*)d_in[15];
  const float* w_g1    = (const float*)d_in[16];
  const float* b_g1    = (const float*)d_in[17];
  const float* w_g2    = (const float*)d_in[18];
  const float* b_g2    = (const float*)d_in[19];

  float* ws    = (float*)d_ws;
  float* XT    = ws + 0;               // 8192*512
  float* PRE   = ws + 4194304;         // 8192*512
  float* INPC  = ws + 8388608;         // 8192*512
  float* Hbuf  = ws + 12582912;        // 8192*512
  float* G1    = ws + 0;               // reuse XT+PRE after scan (8192*1024)
  float* LOGB  = ws + 8388608;         // reuse INPC (8192*128)
  float* SM    = ws + 9437184;         // 8192*128
  float* W1cat = ws + 16777216;        // 512*1024
  float* W3    = ws + 17301504;        // 512*512
  float* b3    = ws + 17563648;        // 512
  float* biwc  = ws + 17564160;        // 512
  float* hbuf  = ws + 17564672;        // 4*512
  float* ff1g  = ws + 17566720;        // 4*512
  float* ff2g  = ws + 17568768;        // 4*512
  float* recg  = ws + 17570816;        // 4*512
  int*   bar   = (int*)(ws + 17572864);// 128 ints
  if (ws_size < (size_t)17573000 * sizeof(float)) return;

  // zero h state + barrier flags (fresh every call: deterministic)
  hipMemsetAsync(hbuf, 0, (17572864 + 128 - 17564672) * sizeof(float), stream);

  pack_k<<<2048, 256, 0, stream>>>(w_ff1, w_rw, w_ta, w_tb, b_ta, b_tb, b_iw, input_b,
                                   W1cat, W3, b3, biwc);
  // xt for all (b,t)
  gemm_k<false><<<dim3(8, 128), 256, 0, stream>>>(x, w_in, b_in, XT, NROW, 512, 4096);
  // ff1 xt-part (+b_ff1) and inp_c
  gemm_k<false><<<dim3(8, 128), 256, 0, stream>>>(XT, w_ff1, b_ff1, PRE, NROW, 512, 512);
  gemm_k<true ><<<dim3(8, 128), 256, 0, stream>>>(XT, w_iw, biwc, INPC, NROW, 512, 512);
  // sequential recurrence
  scan_k<<<SCAN_BLOCKS, 256, 0, stream>>>(W1cat, w_ff2, b_ff2, W3, b3, r_b,
                                          PRE, INPC, Hbuf, hbuf, ff1g, ff2g, recg, bar);
  // gate
  gemm_k<true ><<<dim3(16, 128), 256, 0, stream>>>(Hbuf, w_g1, b_g1, G1, NROW, 1024, 512);
  gemm_k<false><<<dim3(2, 128), 256, 0, stream>>>(G1, w_g2, b_g2, LOGB, NROW, 128, 1024);
  softmax_k<<<2048, 256, 0, stream>>>(LOGB, SM);
  smooth_topk_k<<<2048, 256, 0, stream>>>(SM, (float*)d_out);
}

// Round 2
// 10956.285 us; speedup vs baseline: 2.0082x; 2.0082x over previous
//
#include <hip/hip_runtime.h>
#include <cmath>

#define HID 512
#define NEXP 128
#define BB 4
#define SS 2048
#define NROW (BB*SS)      // 8192
#define SCAN_BLOCKS 128   // 32 blocks per batch chain, 16 cols each

typedef unsigned long long u64;
typedef unsigned int u32;

__device__ __forceinline__ float gelu_f(float x){
  return 0.5f*x*(1.0f + erff(x*0.70710678118654752440f));
}

__device__ __forceinline__ u64 aload64(const u64* p){
  return __hip_atomic_load(p, __ATOMIC_RELAXED, __HIP_MEMORY_SCOPE_AGENT);
}
__device__ __forceinline__ void astore64(u64* p, u64 v){
  __hip_atomic_store(p, v, __ATOMIC_RELAXED, __HIP_MEMORY_SCOPE_AGENT);
}
__device__ __forceinline__ u64 packtag(float f, u32 tag){
  return ((u64)__float_as_uint(f) << 32) | (u64)tag;
}

// poll 2 assigned words until both carry `tag`, deposit payloads into stg
__device__ __forceinline__ void poll2(const u64* exbuf, u32 tag, float* stg, int tid){
  const u64* p0 = exbuf + tid;
  const u64* p1 = exbuf + tid + 256;
  u64 v0 = aload64(p0);
  u64 v1 = aload64(p1);
  while ((u32)v0 != tag) v0 = aload64(p0);
  while ((u32)v1 != tag) v1 = aload64(p1);
  stg[tid]       = __uint_as_float((u32)(v0 >> 32));
  stg[tid + 256] = __uint_as_float((u32)(v1 >> 32));
}

// ---------------- biwc = b_iw + input_b --------------------------------------
__global__ __launch_bounds__(256) void biwc_k(const float* __restrict__ b_iw,
                                              const float* __restrict__ input_b,
                                              float* __restrict__ biwc)
{
  int i = blockIdx.x*256 + threadIdx.x;
  if (i < HID) biwc[i] = b_iw[i] + input_b[i];
}

// ---------------- generic fp32 GEMM: C = A(MxK) @ W(KxN) + bias (opt gelu) --
template<bool GELU>
__global__ __launch_bounds__(256) void gemm_k(
    const float* __restrict__ A, const float* __restrict__ W,
    const float* __restrict__ bias, float* __restrict__ C,
    int M, int N, int K)
{
  __shared__ float As[16][68];
  __shared__ float Ws[16][68];
  const int tid = threadIdx.x;
  const int mb = blockIdx.y*64, nb = blockIdx.x*64;
  const int tx = tid & 15, ty = tid >> 4;
  const int am = tid >> 2, ak = (tid & 3)*4;
  const int wk = tid >> 4, wn = (tid & 15)*4;
  float acc[4][4] = {};
  const float* Aptr = A + (size_t)(mb+am)*K + ak;
  for (int kt = 0; kt < K; kt += 16){
    float4 av = *(const float4*)(Aptr + kt);
    float4 wv = *(const float4*)(W + (size_t)(kt+wk)*N + nb + wn);
    As[ak  ][am] = av.x; As[ak+1][am] = av.y; As[ak+2][am] = av.z; As[ak+3][am] = av.w;
    *(float4*)&Ws[wk][wn] = wv;
    __syncthreads();
#pragma unroll
    for (int kk = 0; kk < 16; kk++){
      float4 a4 = *(const float4*)&As[kk][ty*4];
      float4 w4 = *(const float4*)&Ws[kk][tx*4];
      float ar[4] = {a4.x, a4.y, a4.z, a4.w};
      float wr[4] = {w4.x, w4.y, w4.z, w4.w};
#pragma unroll
      for (int i = 0; i < 4; i++)
#pragma unroll
        for (int j = 0; j < 4; j++)
          acc[i][j] = fmaf(ar[i], wr[j], acc[i][j]);
    }
    __syncthreads();
  }
#pragma unroll
  for (int i = 0; i < 4; i++){
    int row = mb + ty*4 + i;
    float o[4];
#pragma unroll
    for (int j = 0; j < 4; j++){
      float v = acc[i][j] + bias[nb + tx*4 + j];
      o[j] = GELU ? gelu_f(v) : v;
    }
    float4 o4 = {o[0], o[1], o[2], o[3]};
    *(float4*)(C + (size_t)row*N + nb + tx*4) = o4;
  }
}

// ---------------- sequential h-recurrence (tagged-data exchange) -------------
__global__ __launch_bounds__(256, 1) void scan_k(
    const float* __restrict__ w_ff1, const float* __restrict__ w_rw,
    const float* __restrict__ w_ff2,
    const float* __restrict__ w_ta, const float* __restrict__ w_tb,
    const float* __restrict__ bff2, const float* __restrict__ b_ta,
    const float* __restrict__ b_tb, const float* __restrict__ rb,
    const float* __restrict__ PRE, const float* __restrict__ INPC,
    float* __restrict__ Hout,
    u64* __restrict__ exh, u64* __restrict__ exf1, u64* __restrict__ exf2)
{
  // paired-k layouts: Wa2[k2][c=0..31][e], Wb2/Wc2[k2][c=0..15][e]
  __shared__ float Wa2[512*32];   // 64 KB
  __shared__ float Wb2[512*16];   // 32 KB
  __shared__ float Wc2[512*16];   // 32 KB
  __shared__ float stg[512];
  __shared__ float red[128];
  __shared__ float rec_loc[16];

  const int tid = threadIdx.x;
  const int b = blockIdx.x >> 5, sub = blockIdx.x & 31;
  const int col0 = sub*16;
  u64* exh_b  = exh  + b*512;
  u64* exf1_b = exf1 + b*512;
  u64* exf2_b = exf2 + b*512;

  // ---- preload weight slices into LDS (paired-k) ----
  for (int idx = tid; idx < 512*32; idx += 256){
    int k = idx >> 5, c = idx & 31;
    float v = (c < 16) ? w_ff1[(size_t)(512+k)*HID + col0 + c]
                       : w_rw[(size_t)k*HID + col0 + (c-16)];
    Wa2[((k>>1)<<6) + (c<<1) + (k&1)] = v;
  }
  for (int idx = tid; idx < 512*16; idx += 256){
    int k = idx >> 4, c = idx & 15;
    Wb2[((k>>1)<<5) + (c<<1) + (k&1)] = w_ff2[(size_t)k*HID + col0 + c];
    Wc2[((k>>1)<<5) + (c<<1) + (k&1)] = w_ta[(size_t)k*HID + col0 + c]
                                      + w_tb[(size_t)k*HID + col0 + c];
  }
  // per-thread constants
  float b3v = 0.f, bff2v = 0.f, rbv = 0.f, h_reg = 0.f;
  if (tid < 16){ b3v = b_ta[col0+tid] + b_tb[col0+tid]; bff2v = bff2[col0+tid]; }
  if (tid >= 16 && tid < 32) rbv = rb[col0 + tid - 16];
  __syncthreads();

  const int cA = tid & 31, pA = tid >> 5;   // stage A: 32 outs x 8 k-parts
  const int cB = tid & 15, pB = tid >> 4;   // stage B/C: 16 outs x 16 k-parts

  for (int t = 0; t < SS; t++){
    // prefetch per-step inputs (latency hides under stage A)
    float pre_v = 0.f, ic_v = 0.f;
    if (tid < 16){
      pre_v = PRE [((size_t)b*SS + t)*HID + col0 + tid];
      ic_v  = INPC[((size_t)b*SS + t)*HID + col0 + tid];
    }
    // ---- gather h (tag t) ----
    poll2(exh_b, (u32)t, stg, tid);
    __syncthreads();
    // ---- stage A: [ff1_h | rec] = h @ Wa ----
    {
      const float2* wp = (const float2*)(Wa2) + (pA<<5) + cA;
      const float2* hp = (const float2*)(stg) + pA;
      float a0=0.f, a1=0.f, a2=0.f, a3=0.f;
#pragma unroll
      for (int j = 0; j < 32; j += 2){
        float2 w0 = wp[(j+0)*256], h0 = hp[(j+0)*8];
        float2 w1 = wp[(j+1)*256], h1 = hp[(j+1)*8];
        a0 = fmaf(w0.x, h0.x, a0); a1 = fmaf(w0.y, h0.y, a1);
        a2 = fmaf(w1.x, h1.x, a2); a3 = fmaf(w1.y, h1.y, a3);
      }
      float acc = (a0+a1)+(a2+a3);
      acc += __shfl_xor(acc, 32);
      if ((tid & 32) == 0) red[(tid>>6)*32 + cA] = acc;
    }
    __syncthreads();
    if (tid < 32){
      float s = red[tid] + red[32+tid] + red[64+tid] + red[96+tid];
      if (tid < 16){
        float v = gelu_f(pre_v + s);
        astore64(&exf1_b[col0 + tid], packtag(v, (u32)(t+1)));
      } else {
        rec_loc[tid-16] = gelu_f(s + rbv);
      }
    }
    // ---- gather ff1 (tag t+1) ----
    poll2(exf1_b, (u32)(t+1), stg, tid);
    __syncthreads();
    // ---- stage B: ff2 = gelu(ff1 @ Wb + b) ----
    {
      const float2* wp = (const float2*)(Wb2) + (pB<<4) + cB;
      const float2* hp = (const float2*)(stg) + pB;
      float a0=0.f, a1=0.f, a2=0.f, a3=0.f;
#pragma unroll
      for (int j = 0; j < 16; j += 2){
        float2 w0 = wp[(j+0)*256], h0 = hp[(j+0)*16];
        float2 w1 = wp[(j+1)*256], h1 = hp[(j+1)*16];
        a0 = fmaf(w0.x, h0.x, a0); a1 = fmaf(w0.y, h0.y, a1);
        a2 = fmaf(w1.x, h1.x, a2); a3 = fmaf(w1.y, h1.y, a3);
      }
      float acc = (a0+a1)+(a2+a3);
      acc += __shfl_xor(acc, 16);
      acc += __shfl_xor(acc, 32);
      if ((tid & 48) == 0) red[(tid>>6)*16 + cB] = acc;
    }
    __syncthreads();
    if (tid < 16){
      float s = red[tid] + red[16+tid] + red[32+tid] + red[48+tid];
      float v = gelu_f(s + bff2v);
      astore64(&exf2_b[col0 + tid], packtag(v, (u32)(t+1)));
    }
    // ---- gather ff2 (tag t+1) ----
    poll2(exf2_b, (u32)(t+1), stg, tid);
    __syncthreads();
    // ---- stage C: t_interp + new_h ----
    {
      const float2* wp = (const float2*)(Wc2) + (pB<<4) + cB;
      const float2* hp = (const float2*)(stg) + pB;
      float a0=0.f, a1=0.f, a2=0.f, a3=0.f;
#pragma unroll
      for (int j = 0; j < 16; j += 2){
        float2 w0 = wp[(j+0)*256], h0 = hp[(j+0)*16];
        float2 w1 = wp[(j+1)*256], h1 = hp[(j+1)*16];
        a0 = fmaf(w0.x, h0.x, a0); a1 = fmaf(w0.y, h0.y, a1);
        a2 = fmaf(w1.x, h1.x, a2); a3 = fmaf(w1.y, h1.y, a3);
      }
      float acc = (a0+a1)+(a2+a3);
      acc += __shfl_xor(acc, 16);
      acc += __shfl_xor(acc, 32);
      if ((tid & 48) == 0) red[(tid>>6)*16 + cB] = acc;
    }
    __syncthreads();
    if (tid < 16){
      float s = red[tid] + red[16+tid] + red[32+tid] + red[48+tid];
      float ti = 1.0f / (1.0f + expf(-(s + b3v)));
      float nh = h_reg*(1.0f - ti) + ti*(ic_v + rec_loc[tid]);
      h_reg = nh;
      astore64(&exh_b[col0 + tid], packtag(nh, (u32)(t+1)));
      Hout[((size_t)b*SS + t)*HID + col0 + tid] = nh;
    }
  }
}

// ---------------- softmax over 128 experts ----------------------------------
__global__ __launch_bounds__(256) void softmax_k(const float* __restrict__ LOGITS,
                                                 float* __restrict__ SM)
{
  int wv = threadIdx.x >> 6, lane = threadIdx.x & 63;
  int row = blockIdx.x*4 + wv;
  const float* xp = LOGITS + (size_t)row*NEXP;
  float x0 = xp[lane], x1 = xp[lane+64];
  float m = fmaxf(x0, x1);
#pragma unroll
  for (int d = 1; d < 64; d <<= 1) m = fmaxf(m, __shfl_xor(m, d));
  float e0 = expf(x0 - m), e1 = expf(x1 - m);
  float s = e0 + e1;
#pragma unroll
  for (int d = 1; d < 64; d <<= 1) s += __shfl_xor(s, d);
  float inv = 1.0f / s;
  float* op = SM + (size_t)row*NEXP;
  op[lane] = e0*inv; op[lane+64] = e1*inv;
}

// ---------------- smoothing (20-term window == exact recurrence) + top2 -----
__global__ __launch_bounds__(256) void smooth_topk_k(const float* __restrict__ SM,
                                                     float* __restrict__ out)
{
  int wv = threadIdx.x >> 6, lane = threadIdx.x & 63;
  int row = blockIdx.x*4 + wv;
  int b = row >> 11, t = row & 2047;
  const float* base = SM + (size_t)row*NEXP;
  float a0 = 0.f, a1 = 0.f;
  float coef = 0.9f;
  int nt = t < 20 ? t : 20;
  for (int j = 0; j < nt; j++){
    const float* pj = base - j*NEXP;
    a0 += coef * pj[lane];
    a1 += coef * pj[lane+64];
    coef *= 0.1f;
  }
  if (t < 20){
    const float* s0 = SM + (size_t)b*SS*NEXP;
    float c0 = coef * (1.0f/0.9f);    // 0.1^t
    a0 += c0 * s0[lane];
    a1 += c0 * s0[lane+64];
  }
  float v0, v1; int i0, i1;
  if (a0 >= a1){ v0=a0; i0=lane;    v1=a1; i1=lane+64; }
  else         { v0=a1; i0=lane+64; v1=a0; i1=lane;    }
#pragma unroll
  for (int d = 1; d < 64; d <<= 1){
    float ov0 = __shfl_xor(v0, d), ov1 = __shfl_xor(v1, d);
    int   oi0 = __shfl_xor(i0, d), oi1 = __shfl_xor(i1, d);
    bool firstMine = (v0 > ov0) || (v0 == ov0 && i0 < oi0);
    float nv0, nv1; int ni0, ni1;
    if (firstMine){
      nv0 = v0; ni0 = i0;
      bool s = (v1 > ov0) || (v1 == ov0 && i1 < oi0);
      nv1 = s ? v1 : ov0; ni1 = s ? i1 : oi0;
    } else {
      nv0 = ov0; ni0 = oi0;
      bool s = (ov1 > v0) || (ov1 == v0 && oi1 < i0);
      nv1 = s ? ov1 : v0; ni1 = s ? oi1 : i0;
    }
    v0 = nv0; v1 = nv1; i0 = ni0; i1 = ni1;
  }
  if (lane == 0){
    float ssum = v0 + v1;
    size_t o = (size_t)row*2;
    out[o]     = (float)i0;
    out[o+1]   = (float)i1;
    out[16384 + o]   = v0 / ssum;
    out[16384 + o+1] = v1 / ssum;
  }
}

// ---------------- host launch ------------------------------------------------
extern "C" void kernel_launch(void* const* d_in, const int* in_sizes, int n_in,
                              void* d_out, int out_size, void* d_ws, size_t ws_size,
                              hipStream_t stream)
{
  (void)in_sizes; (void)n_in; (void)out_size;
  const float* x       = (const float*)d_in[0];
  const float* w_in    = (const float*)d_in[1];
  const float* b_in    = (const float*)d_in[2];
  const float* w_ff1   = (const float*)d_in[3];
  const float* b_ff1   = (const float*)d_in[4];
  const float* w_ff2   = (const float*)d_in[5];
  const float* b_ff2   = (const float*)d_in[6];
  const float* w_ta    = (const float*)d_in[7];
  const float* b_ta    = (const float*)d_in[8];
  const float* w_tb    = (const float*)d_in[9];
  const float* b_tb    = (const float*)d_in[10];
  const float* w_iw    = (const float*)d_in[11];
  const float* b_iw    = (const float*)d_in[12];
  const float* input_b = (const float*)d_in[13];
  const float* w_rw    = (const float*)d_in[14];
  const float* r_b     = (const float*)d_in[15];
  const float* w_g1    = (const float*)d_in[16];
  const float* b_g1    = (const float*)d_in[17];
  const float* w_g2    = (const float*)d_in[18];
  const float* b_g2    = (const float*)d_in[19];

  float* ws    = (float*)d_ws;
  float* XT    = ws + 0;               // 8192*512
  float* PRE   = ws + 4194304;         // 8192*512
  float* INPC  = ws + 8388608;         // 8192*512
  float* Hbuf  = ws + 12582912;        // 8192*512
  float* G1    = ws + 0;               // reuse XT+PRE after scan (8192*1024)
  float* LOGB  = ws + 8388608;         // reuse INPC (8192*128)
  float* SM    = ws + 9437184;         // 8192*128
  float* biwc  = ws + 16777216;        // 512
  u64*   exh   = (u64*)(ws + 16777728);// 4*512 u64
  u64*   exf1  = (u64*)(ws + 16781824);
  u64*   exf2  = (u64*)(ws + 16785920);
  if (ws_size < (size_t)16790016 * sizeof(float)) return;

  // reset exchange tags (fresh every call: deterministic, graph-replay safe)
  hipMemsetAsync(ws + 16777728, 0, 3 * 2048 * sizeof(u64), stream);

  biwc_k<<<2, 256, 0, stream>>>(b_iw, input_b, biwc);
  // xt for all (b,t)
  gemm_k<false><<<dim3(8, 128), 256, 0, stream>>>(x, w_in, b_in, XT, NROW, 512, 4096);
  // ff1 xt-part (+b_ff1) and inp_c
  gemm_k<false><<<dim3(8, 128), 256, 0, stream>>>(XT, w_ff1, b_ff1, PRE, NROW, 512, 512);
  gemm_k<true ><<<dim3(8, 128), 256, 0, stream>>>(XT, w_iw, biwc, INPC, NROW, 512, 512);
  // sequential recurrence
  scan_k<<<SCAN_BLOCKS, 256, 0, stream>>>(w_ff1, w_rw, w_ff2, w_ta, w_tb,
                                          b_ff2, b_ta, b_tb, r_b,
                                          PRE, INPC, Hbuf, exh, exf1, exf2);
  // gate
  gemm_k<true ><<<dim3(16, 128), 256, 0, stream>>>(Hbuf, w_g1, b_g1, G1, NROW, 1024, 512);
  gemm_k<false><<<dim3(2, 128), 256, 0, stream>>>(G1, w_g2, b_g2, LOGB, NROW, 128, 1024);
  softmax_k<<<2048, 256, 0, stream>>>(LOGB, SM);
  smooth_topk_k<<<2048, 256, 0, stream>>>(SM, (float*)d_out);
}